// Round 5
// baseline (5351.617 us; speedup 1.0000x reference)
//
#include <hip/hip_runtime.h>

// Bidirectional 3-layer GRU encoder, wavefront-scheduled over (layer, time)
// anti-diagonals. 130 stage kernels; each stage computes up to 3 cells x 2
// directions with bf16 MFMA (fp32 accum), fp32 gate math, fp32 master h.
//
// Round 5: compiler-safe reg-staged double buffer (T14). Per chunk (BK=64):
// issue global loads for chunk ci+1 into VGPRs, compute chunk ci from LDS,
// ds_write chunk ci+1, ONE __syncthreads. No raw barriers / counted vmcnt
// (round 4's hand-scheduled pipeline raced under replay timing).
// LDS row stride padded to 72 elems (144 B) -> bank-access floor on both
// ds_write_b128 and ds_read_b128 (verified by bank arithmetic), no swizzle.
// Tile 64 rows x 192 gate-cols per block, 2 waves; grid 384 = 6 x 8mt x 8ht.

typedef short bf16x8 __attribute__((ext_vector_type(8)));
typedef float f32x4 __attribute__((ext_vector_type(4)));
typedef unsigned short u16;

#define TT 128
#define BB 512
#define DD 300
#define DP 320
#define HH 512
#define G3 1536
#define NSTAGE (TT + 2)   // 130
#define LDSP 72           // padded LDS row stride (u16 elems) for BK=64

__device__ __forceinline__ u16 f2b(float f) {
  union { float f; unsigned u; } v; v.f = f;
  unsigned r = (v.u + 0x7fffu + ((v.u >> 16) & 1u)) >> 16;
  return (u16)r;
}

__global__ void k_cvt(const float* __restrict__ in, u16* __restrict__ out, int n) {
  int i = blockIdx.x * 256 + threadIdx.x;
  if (i < n) out[i] = f2b(in[i]);
}

// row-major [rows][ic] f32 -> [rows][oc] bf16, zero-padded cols ic..oc
__global__ void k_cvt_pad(const float* __restrict__ in, u16* __restrict__ out,
                          int rows, int ic, int oc) {
  int i = blockIdx.x * 256 + threadIdx.x;
  if (i >= rows * oc) return;
  int r = i / oc, c = i - r * oc;
  out[i] = (c < ic) ? f2b(in[(size_t)r * ic + c]) : (u16)0;
}

// vectorized x4 conversion for X: [rows][300] f32 -> [rows][320] bf16
__global__ void k_cvt_pad4(const float* __restrict__ in, u16* __restrict__ out,
                           int rows) {
  int i = blockIdx.x * 256 + threadIdx.x;   // over rows*80 ushort4 units
  if (i >= rows * 80) return;
  int r = i / 80, c4 = i - r * 80;
  ushort4 o;
  if (c4 < 75) {
    const float4 v = *(const float4*)(in + (size_t)r * DD + c4 * 4);
    o.x = f2b(v.x); o.y = f2b(v.y); o.z = f2b(v.z); o.w = f2b(v.w);
  } else {
    o.x = o.y = o.z = o.w = 0;
  }
  *(ushort4*)(out + (size_t)r * DP + c4 * 4) = o;
}

struct StageParams {
  const u16* Xb;      // [TT][BB][DP] bf16
  const u16* Wih0b;   // [2][G3][DP]
  const u16* Whh0b;   // [2][G3][HH]
  const u16* Wihb;    // [2][2][G3][HH]  (dir, layer-1)
  const u16* Whhb;    // [2][2][G3][HH]
  float* hf0; float* hf1;   // parity buffers: [6 slots = dir*3+l][BB][HH] f32
  u16*   hb0; u16*   hb1;   // bf16 mirrors
  const float* bih[6];
  const float* bhh[6];
};

__device__ __forceinline__ f32x4 mfma16(bf16x8 a, bf16x8 b, f32x4 c) {
  return __builtin_amdgcn_mfma_f32_16x16x32_bf16(a, b, c, 0, 0, 0);
}

// one K=64 chunk: 48 MFMA, 4 A-reads, 24 B-reads (padded stride: floor-conflict)
__device__ __forceinline__ void do_chunk64(const u16* __restrict__ As_,
                                           const u16* __restrict__ Bs_,
                                           int w, int am, int kq,
                                           f32x4 (&rs)[2][4], f32x4 (&zs)[2][4],
                                           f32x4 (&nn)[2][4]) {
  #pragma unroll
  for (int k = 0; k < 2; ++k) {
    bf16x8 a0 = *(const bf16x8*)(As_ + (w * 32 + 0 * 16 + am) * LDSP + k * 32 + kq * 8);
    bf16x8 a1 = *(const bf16x8*)(As_ + (w * 32 + 1 * 16 + am) * LDSP + k * 32 + kq * 8);
    #pragma unroll
    for (int hc = 0; hc < 4; ++hc) {
      bf16x8 b0 = *(const bf16x8*)(Bs_ + (0 * 64 + hc * 16 + am) * LDSP + k * 32 + kq * 8);
      bf16x8 b1 = *(const bf16x8*)(Bs_ + (1 * 64 + hc * 16 + am) * LDSP + k * 32 + kq * 8);
      bf16x8 b2 = *(const bf16x8*)(Bs_ + (2 * 64 + hc * 16 + am) * LDSP + k * 32 + kq * 8);
      rs[0][hc] = mfma16(a0, b0, rs[0][hc]);
      rs[1][hc] = mfma16(a1, b0, rs[1][hc]);
      zs[0][hc] = mfma16(a0, b1, zs[0][hc]);
      zs[1][hc] = mfma16(a1, b1, zs[1][hc]);
      nn[0][hc] = mfma16(a0, b2, nn[0][hc]);
      nn[1][hc] = mfma16(a1, b2, nn[1][hc]);
    }
  }
}

// grid: 384 blocks = cd(6) x mt(8) x ht(8); 128 threads (2 waves).
__global__ __launch_bounds__(128, 1) void k_stage(int s, StageParams P) {
  __shared__ u16 As[2][64 * LDSP];    // 2 x 9 KB
  __shared__ u16 Bs[2][192 * LDSP];   // 2 x 27 KB   (total 72 KB)

  int bid = blockIdx.x;
  int ht = bid & 7;
  int mt = (bid >> 3) & 7;
  int cd = bid >> 6;             // 0..5
  int dir = cd / 3, cell = cd % 3;
  int t = s - cell;
  if (t < 0 || t >= TT) return;

  int p = s & 1;  // read parity
  const float* hf_in  = p ? P.hf1 : P.hf0;
  float*       hf_out = p ? P.hf0 : P.hf1;
  const u16*   hb_in  = p ? P.hb1 : P.hb0;
  u16*         hb_out = p ? P.hb0 : P.hb1;

  int lane = threadIdx.x & 63;
  int w = threadIdx.x >> 6;      // 0..1
  int am = lane & 15;
  int kq = lane >> 4;            // 0..3
  int slot = dir * 3 + cell;
  int hcol0 = ht * 64;
  int row0g = mt * 64;

  // operand bases (row offset mt*64 folded into A pointers)
  const char* Ah_ = (const char*)(hb_in + (size_t)slot * BB * HH + (size_t)row0g * HH);
  const char* Ax_; int ldax2; const char* Bx_; int ldbx2;
  int nxc;   // x-seg K64 chunk count
  if (cell == 0) {
    int tx = dir ? (TT - 1 - t) : t;
    Ax_ = (const char*)(P.Xb + ((size_t)tx * BB + row0g) * DP); ldax2 = DP * 2;
    Bx_ = (const char*)(P.Wih0b + (size_t)dir * G3 * DP);       ldbx2 = DP * 2;
    nxc = DP / 64;   // 5
  } else {
    Ax_ = (const char*)(hb_in + (size_t)(slot - 1) * BB * HH + (size_t)row0g * HH); ldax2 = HH * 2;
    Bx_ = (const char*)(P.Wihb + (size_t)(dir * 2 + cell - 1) * G3 * HH);           ldbx2 = HH * 2;
    nxc = HH / 64;   // 8
  }
  const char* Bh_ = (const char*)((cell == 0) ? (P.Whh0b + (size_t)dir * G3 * HH)
                                              : (P.Whhb + (size_t)(dir * 2 + cell - 1) * G3 * HH));
  const int NHC = HH / 64;       // 8 h-seg chunks
  const int NC = NHC + nxc;      // 13 or 16

  // per-lane source byte offsets for the 16 staged 16B units
  // A unit u = (w*4+j)*64 + lane : row = u>>3, slot = u&7   (64 rows x 8 slots)
  // B unit u = (w*12+j)*64 + lane: tr  = u>>3, slot = u&7   (192 t-rows x 8 slots)
  int aoffh[4], aoffx[4], boffh[12], boffx[12];
  int arow[4], asl[4], btr[12], bsl[12];
  #pragma unroll
  for (int j = 0; j < 4; ++j) {
    int u = (w * 4 + j) * 64 + lane;
    arow[j] = u >> 3; asl[j] = u & 7;
    aoffh[j] = arow[j] * (HH * 2) + asl[j] * 16;
    aoffx[j] = arow[j] * ldax2 + asl[j] * 16;
  }
  #pragma unroll
  for (int j = 0; j < 12; ++j) {
    int u = (w * 12 + j) * 64 + lane;
    btr[j] = u >> 3; bsl[j] = u & 7;
    int grow = (btr[j] >> 6) * HH + hcol0 + (btr[j] & 63);
    boffh[j] = grow * (HH * 2) + bsl[j] * 16;
    boffx[j] = grow * ldbx2 + bsl[j] * 16;
  }

  bf16x8 sA[4], sB[12];

  auto loadc = [&](int ci) {
    const char* Ag; const char* Bg; const int* ao; const int* bo; int kcb;
    if (ci < NHC) { Ag = Ah_; Bg = Bh_; ao = aoffh; bo = boffh; kcb = ci * 128; }
    else          { Ag = Ax_; Bg = Bx_; ao = aoffx; bo = boffx; kcb = (ci - NHC) * 128; }
    #pragma unroll
    for (int j = 0; j < 4; ++j)  sA[j] = *(const bf16x8*)(Ag + (size_t)(ao[j] + kcb));
    #pragma unroll
    for (int j = 0; j < 12; ++j) sB[j] = *(const bf16x8*)(Bg + (size_t)(bo[j] + kcb));
  };

  auto store = [&](int pb) {
    u16* Ad = &As[pb][0];
    u16* Bd = &Bs[pb][0];
    #pragma unroll
    for (int j = 0; j < 4; ++j)
      *(bf16x8*)(Ad + arow[j] * LDSP + asl[j] * 8) = sA[j];
    #pragma unroll
    for (int j = 0; j < 12; ++j)
      *(bf16x8*)(Bd + btr[j] * LDSP + bsl[j] * 8) = sB[j];
  };

  f32x4 rs[2][4] = {}, zs[2][4] = {}, nx[2][4] = {}, nh[2][4] = {};

  loadc(0);
  store(0);
  __syncthreads();
  int pb = 0;
  for (int ci = 0; ci < NC; ++ci) {
    bool more = (ci + 1 < NC);
    if (more) loadc(ci + 1);            // VMEM in flight under compute
    if (ci < NHC) do_chunk64(&As[pb][0], &Bs[pb][0], w, am, kq, rs, zs, nh);
    else          do_chunk64(&As[pb][0], &Bs[pb][0], w, am, kq, rs, zs, nx);
    if (more) {
      store(pb ^ 1);                    // compiler waits vmcnt before ds_write
      __syncthreads();
      pb ^= 1;
    }
  }

  // gates + state update (fp32)
  const float* bihp = P.bih[slot];
  const float* bhhp = P.bhh[slot];
  const float* hin  = hf_in  + (size_t)slot * BB * HH;
  float*       hout = hf_out + (size_t)slot * BB * HH;
  u16*         bout = hb_out + (size_t)slot * BB * HH;

  #pragma unroll
  for (int hc = 0; hc < 4; ++hc) {
    int col = hcol0 + hc * 16 + am;
    float bir = bihp[col],          bhr = bhhp[col];
    float biz = bihp[HH + col],     bhz = bhhp[HH + col];
    float bin = bihp[2 * HH + col], bhn = bhhp[2 * HH + col];
    #pragma unroll
    for (int fr = 0; fr < 2; ++fr) {
      #pragma unroll
      for (int reg = 0; reg < 4; ++reg) {
        int row = row0g + w * 32 + fr * 16 + kq * 4 + reg;
        float rg = 1.f / (1.f + __expf(-(rs[fr][hc][reg] + bir + bhr)));
        float zg = 1.f / (1.f + __expf(-(zs[fr][hc][reg] + biz + bhz)));
        float ng = tanhf(nx[fr][hc][reg] + bin + rg * (nh[fr][hc][reg] + bhn));
        float hp = hin[(size_t)row * HH + col];
        float hv = (1.f - zg) * ng + zg * hp;
        hout[(size_t)row * HH + col] = hv;
        bout[(size_t)row * HH + col] = f2b(hv);
      }
    }
  }
}

struct HeadParams {
  const u16* Wmub;   // [HH][2*HH] bf16
  const u16* Wlvb;
  const u16* hb0;    // final states live in parity-0 buffer (stage 129 writes it)
  const float* bmu; const float* blv;
  float* out;        // [2][BB][HH]: mu then logvar
};

// grid: 128 blocks = which(2) x rowtile(8) x coltile(8)
__global__ __launch_bounds__(256, 2) void k_head(HeadParams P) {
  int bid = blockIdx.x;
  int ct = bid & 7, rt = (bid >> 3) & 7, which = bid >> 6;
  int lane = threadIdx.x & 63, w = threadIdx.x >> 6;
  int rbase = rt * 64 + w * 16, cbase = ct * 64;
  const u16* Wb = which ? P.Wlvb : P.Wmub;
  const float* bias = which ? P.blv : P.bmu;
  const u16* Afw = P.hb0 + (size_t)2 * BB * HH;   // slot 2 = fw layer2
  const u16* Abw = P.hb0 + (size_t)5 * BB * HH;   // slot 5 = bw layer2
  int am = lane & 15, koff = (lane >> 4) * 8;
  f32x4 acc[4] = {};
  const u16* a0 = Afw + (size_t)(rbase + am) * HH + koff;
  const u16* a1 = Abw + (size_t)(rbase + am) * HH + koff;
  #pragma unroll 1
  for (int kc = 0; kc < HH; kc += 32) {
    bf16x8 a = *(const bf16x8*)(a0 + kc);
    #pragma unroll
    for (int c = 0; c < 4; ++c) {
      int n = cbase + c * 16 + am;
      bf16x8 b = *(const bf16x8*)(Wb + (size_t)n * (2 * HH) + koff + kc);
      acc[c] = __builtin_amdgcn_mfma_f32_16x16x32_bf16(a, b, acc[c], 0, 0, 0);
    }
  }
  #pragma unroll 1
  for (int kc = 0; kc < HH; kc += 32) {
    bf16x8 a = *(const bf16x8*)(a1 + kc);
    #pragma unroll
    for (int c = 0; c < 4; ++c) {
      int n = cbase + c * 16 + am;
      bf16x8 b = *(const bf16x8*)(Wb + (size_t)n * (2 * HH) + HH + koff + kc);
      acc[c] = __builtin_amdgcn_mfma_f32_16x16x32_bf16(a, b, acc[c], 0, 0, 0);
    }
  }
  float* out = P.out + (size_t)which * BB * HH;
  int r0 = rbase + (lane >> 4) * 4;
  #pragma unroll
  for (int c = 0; c < 4; ++c) {
    int col = cbase + c * 16 + am;
    float bv = bias[col];
    #pragma unroll
    for (int reg = 0; reg < 4; ++reg) {
      out[(size_t)(r0 + reg) * HH + col] = acc[c][reg] + bv;
    }
  }
}

extern "C" void kernel_launch(void* const* d_in, const int* in_sizes, int n_in,
                              void* d_out, int out_size, void* d_ws, size_t ws_size,
                              hipStream_t stream) {
  (void)in_sizes; (void)n_in; (void)ws_size;
  char* ws = (char*)d_ws;
  size_t off = 0;
  auto alloc = [&](size_t bytes) {
    char* q = ws + off;
    off += (bytes + 255) & ~(size_t)255;
    return q;
  };
  u16* Xb    = (u16*)alloc((size_t)TT * BB * DP * 2);
  u16* Wih0b = (u16*)alloc((size_t)2 * G3 * DP * 2);
  u16* Whh0b = (u16*)alloc((size_t)2 * G3 * HH * 2);
  u16* Wihb  = (u16*)alloc((size_t)4 * G3 * HH * 2);
  u16* Whhb  = (u16*)alloc((size_t)4 * G3 * HH * 2);
  u16* Wmub  = (u16*)alloc((size_t)HH * 2 * HH * 2);
  u16* Wlvb  = (u16*)alloc((size_t)HH * 2 * HH * 2);
  float* hf  = (float*)alloc((size_t)2 * 6 * BB * HH * 4);
  u16*   hb  = (u16*)alloc((size_t)2 * 6 * BB * HH * 2);

  const float* X = (const float*)d_in[0];

  hipMemsetAsync(hf, 0, (size_t)2 * 6 * BB * HH * 4, stream);
  hipMemsetAsync(hb, 0, (size_t)2 * 6 * BB * HH * 2, stream);

  {
    int n4 = TT * BB * 80;
    k_cvt_pad4<<<(n4 + 255) / 256, 256, 0, stream>>>(X, Xb, TT * BB);
    int nw0 = G3 * DP;
    k_cvt_pad<<<(nw0 + 255) / 256, 256, 0, stream>>>((const float*)d_in[2],  Wih0b,                   G3, DD, DP);
    k_cvt_pad<<<(nw0 + 255) / 256, 256, 0, stream>>>((const float*)d_in[10], Wih0b + (size_t)G3 * DP, G3, DD, DP);
    int n1 = G3 * HH;
    k_cvt<<<(n1 + 255) / 256, 256, 0, stream>>>((const float*)d_in[3],  Whh0b,      n1);
    k_cvt<<<(n1 + 255) / 256, 256, 0, stream>>>((const float*)d_in[11], Whh0b + n1, n1);
    int n2 = 2 * G3 * HH;
    k_cvt<<<(n2 + 255) / 256, 256, 0, stream>>>((const float*)d_in[6],  Wihb,      n2);
    k_cvt<<<(n2 + 255) / 256, 256, 0, stream>>>((const float*)d_in[14], Wihb + n2, n2);
    k_cvt<<<(n2 + 255) / 256, 256, 0, stream>>>((const float*)d_in[7],  Whhb,      n2);
    k_cvt<<<(n2 + 255) / 256, 256, 0, stream>>>((const float*)d_in[15], Whhb + n2, n2);
    int n3 = HH * 2 * HH;
    k_cvt<<<(n3 + 255) / 256, 256, 0, stream>>>((const float*)d_in[18], Wmub, n3);
    k_cvt<<<(n3 + 255) / 256, 256, 0, stream>>>((const float*)d_in[20], Wlvb, n3);
  }

  StageParams SP;
  SP.Xb = Xb; SP.Wih0b = Wih0b; SP.Whh0b = Whh0b; SP.Wihb = Wihb; SP.Whhb = Whhb;
  SP.hf0 = hf;                       SP.hf1 = hf + (size_t)6 * BB * HH;
  SP.hb0 = hb;                       SP.hb1 = hb + (size_t)6 * BB * HH;
  SP.bih[0] = (const float*)d_in[4];
  SP.bih[1] = (const float*)d_in[8];
  SP.bih[2] = (const float*)d_in[8] + G3;
  SP.bih[3] = (const float*)d_in[12];
  SP.bih[4] = (const float*)d_in[16];
  SP.bih[5] = (const float*)d_in[16] + G3;
  SP.bhh[0] = (const float*)d_in[5];
  SP.bhh[1] = (const float*)d_in[9];
  SP.bhh[2] = (const float*)d_in[9] + G3;
  SP.bhh[3] = (const float*)d_in[13];
  SP.bhh[4] = (const float*)d_in[17];
  SP.bhh[5] = (const float*)d_in[17] + G3;

  for (int s = 0; s < NSTAGE; ++s) {
    k_stage<<<384, 128, 0, stream>>>(s, SP);
  }

  HeadParams HP;
  HP.Wmub = Wmub; HP.Wlvb = Wlvb; HP.hb0 = hb;
  HP.bmu = (const float*)d_in[19]; HP.blv = (const float*)d_in[21];
  HP.out = (float*)d_out;
  k_head<<<128, 256, 0, stream>>>(HP);
}

// Round 7
// 3967.028 us; speedup vs baseline: 1.3490x; 1.3490x over previous
//
#include <hip/hip_runtime.h>

// Bidirectional 3-layer GRU encoder, wavefront-scheduled over (layer, time)
// anti-diagonals. 130 stage kernels; each stage computes up to 3 cells x 2
// directions with bf16 MFMA (fp32 accum), fp32 gate math, fp32 master h.
//
// Round 6 (resubmit after broker timeout): occupancy fix. 4 waves/block
// (256 thr), tile 64 rows x 192 gate-cols, wave w owns h-cols
// [w*16, w*16+16) x 3 gates (N-split: B-reads 6/chunk/wave, A-reads 8).
// Same compiler-safe reg-staged double buffer as round 5 (one __syncthreads
// per chunk, no raw barriers). 72 KB LDS -> 2 blocks/CU, 8 waves/CU (2/SIMD).

typedef short bf16x8 __attribute__((ext_vector_type(8)));
typedef float f32x4 __attribute__((ext_vector_type(4)));
typedef unsigned short u16;

#define TT 128
#define BB 512
#define DD 300
#define DP 320
#define HH 512
#define G3 1536
#define NSTAGE (TT + 2)   // 130
#define LDSP 72           // padded LDS row stride (u16 elems) for BK=64

__device__ __forceinline__ u16 f2b(float f) {
  union { float f; unsigned u; } v; v.f = f;
  unsigned r = (v.u + 0x7fffu + ((v.u >> 16) & 1u)) >> 16;
  return (u16)r;
}

// vectorized x4 f32 -> bf16 (n % 4 == 0)
__global__ void k_cvt4(const float* __restrict__ in, u16* __restrict__ out, int n4) {
  int i = blockIdx.x * 256 + threadIdx.x;
  if (i >= n4) return;
  const float4 v = *(const float4*)(in + (size_t)i * 4);
  ushort4 o; o.x = f2b(v.x); o.y = f2b(v.y); o.z = f2b(v.z); o.w = f2b(v.w);
  *(ushort4*)(out + (size_t)i * 4) = o;
}

// row-major [rows][ic] f32 -> [rows][oc] bf16, zero-padded cols ic..oc
__global__ void k_cvt_pad(const float* __restrict__ in, u16* __restrict__ out,
                          int rows, int ic, int oc) {
  int i = blockIdx.x * 256 + threadIdx.x;
  if (i >= rows * oc) return;
  int r = i / oc, c = i - r * oc;
  out[i] = (c < ic) ? f2b(in[(size_t)r * ic + c]) : (u16)0;
}

// vectorized x4 conversion for X: [rows][300] f32 -> [rows][320] bf16
__global__ void k_cvt_pad4(const float* __restrict__ in, u16* __restrict__ out,
                           int rows) {
  int i = blockIdx.x * 256 + threadIdx.x;   // over rows*80 ushort4 units
  if (i >= rows * 80) return;
  int r = i / 80, c4 = i - r * 80;
  ushort4 o;
  if (c4 < 75) {
    const float4 v = *(const float4*)(in + (size_t)r * DD + c4 * 4);
    o.x = f2b(v.x); o.y = f2b(v.y); o.z = f2b(v.z); o.w = f2b(v.w);
  } else {
    o.x = o.y = o.z = o.w = 0;
  }
  *(ushort4*)(out + (size_t)r * DP + c4 * 4) = o;
}

struct StageParams {
  const u16* Xb;      // [TT][BB][DP] bf16
  const u16* Wih0b;   // [2][G3][DP]
  const u16* Whh0b;   // [2][G3][HH]
  const u16* Wihb;    // [2][2][G3][HH]  (dir, layer-1)
  const u16* Whhb;    // [2][2][G3][HH]
  float* hf0; float* hf1;   // parity buffers: [6 slots = dir*3+l][BB][HH] f32
  u16*   hb0; u16*   hb1;   // bf16 mirrors
  const float* bih[6];
  const float* bhh[6];
};

__device__ __forceinline__ f32x4 mfma16(bf16x8 a, bf16x8 b, f32x4 c) {
  return __builtin_amdgcn_mfma_f32_16x16x32_bf16(a, b, c, 0, 0, 0);
}

// one K=64 chunk per wave: 24 MFMA, 8 A-reads, 6 B-reads.
// wave w owns h-cols [w*16, w*16+16) across all 3 gates; all 64 A-rows.
__device__ __forceinline__ void do_chunk64(const u16* __restrict__ As_,
                                           const u16* __restrict__ Bs_,
                                           int w, int am, int kq,
                                           f32x4 (&rs)[4], f32x4 (&zs)[4],
                                           f32x4 (&nn)[4]) {
  #pragma unroll
  for (int k = 0; k < 2; ++k) {
    bf16x8 b0 = *(const bf16x8*)(Bs_ + (0 * 64 + w * 16 + am) * LDSP + k * 32 + kq * 8);
    bf16x8 b1 = *(const bf16x8*)(Bs_ + (1 * 64 + w * 16 + am) * LDSP + k * 32 + kq * 8);
    bf16x8 b2 = *(const bf16x8*)(Bs_ + (2 * 64 + w * 16 + am) * LDSP + k * 32 + kq * 8);
    #pragma unroll
    for (int fr = 0; fr < 4; ++fr) {
      bf16x8 a = *(const bf16x8*)(As_ + (fr * 16 + am) * LDSP + k * 32 + kq * 8);
      rs[fr] = mfma16(a, b0, rs[fr]);
      zs[fr] = mfma16(a, b1, zs[fr]);
      nn[fr] = mfma16(a, b2, nn[fr]);
    }
  }
}

// grid: 384 blocks = cd(6) x mt(8) x ht(8); 256 threads (4 waves).
__global__ __launch_bounds__(256, 2) void k_stage(int s, StageParams P) {
  __shared__ u16 As[2][64 * LDSP];    // 2 x 9 KB
  __shared__ u16 Bs[2][192 * LDSP];   // 2 x 27 KB   (total 72 KB)

  int bid = blockIdx.x;
  int ht = bid & 7;
  int mt = (bid >> 3) & 7;
  int cd = bid >> 6;             // 0..5
  int dir = cd / 3, cell = cd % 3;
  int t = s - cell;
  if (t < 0 || t >= TT) return;

  int p = s & 1;  // read parity
  const float* hf_in  = p ? P.hf1 : P.hf0;
  float*       hf_out = p ? P.hf0 : P.hf1;
  const u16*   hb_in  = p ? P.hb1 : P.hb0;
  u16*         hb_out = p ? P.hb0 : P.hb1;

  int tid = threadIdx.x;
  int lane = tid & 63;
  int w = tid >> 6;              // 0..3
  int am = lane & 15;
  int kq = lane >> 4;            // 0..3
  int slot = dir * 3 + cell;
  int hcol0 = ht * 64;
  int row0g = mt * 64;

  // operand bases (row offset mt*64 folded into A pointers)
  const char* Ah_ = (const char*)(hb_in + (size_t)slot * BB * HH + (size_t)row0g * HH);
  const char* Ax_; int ldax2; const char* Bx_; int ldbx2;
  int nxc;   // x-seg K64 chunk count
  if (cell == 0) {
    int tx = dir ? (TT - 1 - t) : t;
    Ax_ = (const char*)(P.Xb + ((size_t)tx * BB + row0g) * DP); ldax2 = DP * 2;
    Bx_ = (const char*)(P.Wih0b + (size_t)dir * G3 * DP);       ldbx2 = DP * 2;
    nxc = DP / 64;   // 5
  } else {
    Ax_ = (const char*)(hb_in + (size_t)(slot - 1) * BB * HH + (size_t)row0g * HH); ldax2 = HH * 2;
    Bx_ = (const char*)(P.Wihb + (size_t)(dir * 2 + cell - 1) * G3 * HH);           ldbx2 = HH * 2;
    nxc = HH / 64;   // 8
  }
  const char* Bh_ = (const char*)((cell == 0) ? (P.Whh0b + (size_t)dir * G3 * HH)
                                              : (P.Whhb + (size_t)(dir * 2 + cell - 1) * G3 * HH));
  const int NHC = HH / 64;       // 8 h-seg chunks
  const int NC = NHC + nxc;      // 13 or 16

  // per-lane source byte offsets for the 8 staged 16B units (256 threads)
  // A unit u = j*256 + tid : row = u>>3, slot = u&7   (64 rows x 8 slots)
  // B unit u = j*256 + tid : tr  = u>>3, slot = u&7   (192 t-rows x 8 slots)
  int aoffh[2], aoffx[2], boffh[6], boffx[6];
  int arow[2], asl[2], btr[6], bsl[6];
  #pragma unroll
  for (int j = 0; j < 2; ++j) {
    int u = j * 256 + tid;
    arow[j] = u >> 3; asl[j] = u & 7;
    aoffh[j] = arow[j] * (HH * 2) + asl[j] * 16;
    aoffx[j] = arow[j] * ldax2 + asl[j] * 16;
  }
  #pragma unroll
  for (int j = 0; j < 6; ++j) {
    int u = j * 256 + tid;
    btr[j] = u >> 3; bsl[j] = u & 7;
    int grow = (btr[j] >> 6) * HH + hcol0 + (btr[j] & 63);
    boffh[j] = grow * (HH * 2) + bsl[j] * 16;
    boffx[j] = grow * ldbx2 + bsl[j] * 16;
  }

  bf16x8 sA[2], sB[6];

  auto loadc = [&](int ci) {
    const char* Ag; const char* Bg; const int* ao; const int* bo; int kcb;
    if (ci < NHC) { Ag = Ah_; Bg = Bh_; ao = aoffh; bo = boffh; kcb = ci * 128; }
    else          { Ag = Ax_; Bg = Bx_; ao = aoffx; bo = boffx; kcb = (ci - NHC) * 128; }
    #pragma unroll
    for (int j = 0; j < 2; ++j) sA[j] = *(const bf16x8*)(Ag + (size_t)(ao[j] + kcb));
    #pragma unroll
    for (int j = 0; j < 6; ++j) sB[j] = *(const bf16x8*)(Bg + (size_t)(bo[j] + kcb));
  };

  auto store = [&](int pb) {
    u16* Ad = &As[pb][0];
    u16* Bd = &Bs[pb][0];
    #pragma unroll
    for (int j = 0; j < 2; ++j)
      *(bf16x8*)(Ad + arow[j] * LDSP + asl[j] * 8) = sA[j];
    #pragma unroll
    for (int j = 0; j < 6; ++j)
      *(bf16x8*)(Bd + btr[j] * LDSP + bsl[j] * 8) = sB[j];
  };

  f32x4 rs[4] = {}, zs[4] = {}, nx[4] = {}, nh[4] = {};

  loadc(0);
  store(0);
  __syncthreads();
  int pb = 0;
  for (int ci = 0; ci < NC; ++ci) {
    bool more = (ci + 1 < NC);
    if (more) loadc(ci + 1);            // VMEM in flight under compute
    if (ci < NHC) do_chunk64(&As[pb][0], &Bs[pb][0], w, am, kq, rs, zs, nh);
    else          do_chunk64(&As[pb][0], &Bs[pb][0], w, am, kq, rs, zs, nx);
    if (more) {
      store(pb ^ 1);                    // compiler waits vmcnt before ds_write
      __syncthreads();
      pb ^= 1;
    }
  }

  // gates + state update (fp32). wave w owns h-col = hcol0 + w*16 + am.
  const float* bihp = P.bih[slot];
  const float* bhhp = P.bhh[slot];
  const float* hin  = hf_in  + (size_t)slot * BB * HH;
  float*       hout = hf_out + (size_t)slot * BB * HH;
  u16*         bout = hb_out + (size_t)slot * BB * HH;

  int col = hcol0 + w * 16 + am;
  float bir = bihp[col],          bhr = bhhp[col];
  float biz = bihp[HH + col],     bhz = bhhp[HH + col];
  float bin = bihp[2 * HH + col], bhn = bhhp[2 * HH + col];
  #pragma unroll
  for (int fr = 0; fr < 4; ++fr) {
    #pragma unroll
    for (int reg = 0; reg < 4; ++reg) {
      int row = row0g + fr * 16 + kq * 4 + reg;
      float rg = 1.f / (1.f + __expf(-(rs[fr][reg] + bir + bhr)));
      float zg = 1.f / (1.f + __expf(-(zs[fr][reg] + biz + bhz)));
      float ng = tanhf(nx[fr][reg] + bin + rg * (nh[fr][reg] + bhn));
      float hp = hin[(size_t)row * HH + col];
      float hv = (1.f - zg) * ng + zg * hp;
      hout[(size_t)row * HH + col] = hv;
      bout[(size_t)row * HH + col] = f2b(hv);
    }
  }
}

struct HeadParams {
  const u16* Wmub;   // [HH][2*HH] bf16
  const u16* Wlvb;
  const u16* hb0;    // final states live in parity-0 buffer (stage 129 writes it)
  const float* bmu; const float* blv;
  float* out;        // [2][BB][HH]: mu then logvar
};

// grid: 128 blocks = which(2) x rowtile(8) x coltile(8)
__global__ __launch_bounds__(256, 2) void k_head(HeadParams P) {
  int bid = blockIdx.x;
  int ct = bid & 7, rt = (bid >> 3) & 7, which = bid >> 6;
  int lane = threadIdx.x & 63, w = threadIdx.x >> 6;
  int rbase = rt * 64 + w * 16, cbase = ct * 64;
  const u16* Wb = which ? P.Wlvb : P.Wmub;
  const float* bias = which ? P.blv : P.bmu;
  const u16* Afw = P.hb0 + (size_t)2 * BB * HH;   // slot 2 = fw layer2
  const u16* Abw = P.hb0 + (size_t)5 * BB * HH;   // slot 5 = bw layer2
  int am = lane & 15, koff = (lane >> 4) * 8;
  f32x4 acc[4] = {};
  const u16* a0 = Afw + (size_t)(rbase + am) * HH + koff;
  const u16* a1 = Abw + (size_t)(rbase + am) * HH + koff;
  #pragma unroll 1
  for (int kc = 0; kc < HH; kc += 32) {
    bf16x8 a = *(const bf16x8*)(a0 + kc);
    #pragma unroll
    for (int c = 0; c < 4; ++c) {
      int n = cbase + c * 16 + am;
      bf16x8 b = *(const bf16x8*)(Wb + (size_t)n * (2 * HH) + koff + kc);
      acc[c] = __builtin_amdgcn_mfma_f32_16x16x32_bf16(a, b, acc[c], 0, 0, 0);
    }
  }
  #pragma unroll 1
  for (int kc = 0; kc < HH; kc += 32) {
    bf16x8 a = *(const bf16x8*)(a1 + kc);
    #pragma unroll
    for (int c = 0; c < 4; ++c) {
      int n = cbase + c * 16 + am;
      bf16x8 b = *(const bf16x8*)(Wb + (size_t)n * (2 * HH) + HH + koff + kc);
      acc[c] = __builtin_amdgcn_mfma_f32_16x16x32_bf16(a, b, acc[c], 0, 0, 0);
    }
  }
  float* out = P.out + (size_t)which * BB * HH;
  int r0 = rbase + (lane >> 4) * 4;
  #pragma unroll
  for (int c = 0; c < 4; ++c) {
    int col = cbase + c * 16 + am;
    float bv = bias[col];
    #pragma unroll
    for (int reg = 0; reg < 4; ++reg) {
      out[(size_t)(r0 + reg) * HH + col] = acc[c][reg] + bv;
    }
  }
}

extern "C" void kernel_launch(void* const* d_in, const int* in_sizes, int n_in,
                              void* d_out, int out_size, void* d_ws, size_t ws_size,
                              hipStream_t stream) {
  (void)in_sizes; (void)n_in; (void)ws_size;
  char* ws = (char*)d_ws;
  size_t off = 0;
  auto alloc = [&](size_t bytes) {
    char* q = ws + off;
    off += (bytes + 255) & ~(size_t)255;
    return q;
  };
  u16* Xb    = (u16*)alloc((size_t)TT * BB * DP * 2);
  u16* Wih0b = (u16*)alloc((size_t)2 * G3 * DP * 2);
  u16* Whh0b = (u16*)alloc((size_t)2 * G3 * HH * 2);
  u16* Wihb  = (u16*)alloc((size_t)4 * G3 * HH * 2);
  u16* Whhb  = (u16*)alloc((size_t)4 * G3 * HH * 2);
  u16* Wmub  = (u16*)alloc((size_t)HH * 2 * HH * 2);
  u16* Wlvb  = (u16*)alloc((size_t)HH * 2 * HH * 2);
  float* hf  = (float*)alloc((size_t)2 * 6 * BB * HH * 4);
  u16*   hb  = (u16*)alloc((size_t)2 * 6 * BB * HH * 2);

  const float* X = (const float*)d_in[0];

  hipMemsetAsync(hf, 0, (size_t)2 * 6 * BB * HH * 4, stream);
  hipMemsetAsync(hb, 0, (size_t)2 * 6 * BB * HH * 2, stream);

  {
    int n4 = TT * BB * 80;
    k_cvt_pad4<<<(n4 + 255) / 256, 256, 0, stream>>>(X, Xb, TT * BB);
    int nw0 = G3 * DP;
    k_cvt_pad<<<(nw0 + 255) / 256, 256, 0, stream>>>((const float*)d_in[2],  Wih0b,                   G3, DD, DP);
    k_cvt_pad<<<(nw0 + 255) / 256, 256, 0, stream>>>((const float*)d_in[10], Wih0b + (size_t)G3 * DP, G3, DD, DP);
    int n1 = G3 * HH / 4;
    k_cvt4<<<(n1 + 255) / 256, 256, 0, stream>>>((const float*)d_in[3],  Whh0b,          n1);
    k_cvt4<<<(n1 + 255) / 256, 256, 0, stream>>>((const float*)d_in[11], Whh0b + n1 * 4, n1);
    int n2 = 2 * G3 * HH / 4;
    k_cvt4<<<(n2 + 255) / 256, 256, 0, stream>>>((const float*)d_in[6],  Wihb,          n2);
    k_cvt4<<<(n2 + 255) / 256, 256, 0, stream>>>((const float*)d_in[14], Wihb + n2 * 4, n2);
    k_cvt4<<<(n2 + 255) / 256, 256, 0, stream>>>((const float*)d_in[7],  Whhb,          n2);
    k_cvt4<<<(n2 + 255) / 256, 256, 0, stream>>>((const float*)d_in[15], Whhb + n2 * 4, n2);
    int n3 = HH * 2 * HH / 4;
    k_cvt4<<<(n3 + 255) / 256, 256, 0, stream>>>((const float*)d_in[18], Wmub, n3);
    k_cvt4<<<(n3 + 255) / 256, 256, 0, stream>>>((const float*)d_in[20], Wlvb, n3);
  }

  StageParams SP;
  SP.Xb = Xb; SP.Wih0b = Wih0b; SP.Whh0b = Whh0b; SP.Wihb = Wihb; SP.Whhb = Whhb;
  SP.hf0 = hf;                       SP.hf1 = hf + (size_t)6 * BB * HH;
  SP.hb0 = hb;                       SP.hb1 = hb + (size_t)6 * BB * HH;
  SP.bih[0] = (const float*)d_in[4];
  SP.bih[1] = (const float*)d_in[8];
  SP.bih[2] = (const float*)d_in[8] + G3;
  SP.bih[3] = (const float*)d_in[12];
  SP.bih[4] = (const float*)d_in[16];
  SP.bih[5] = (const float*)d_in[16] + G3;
  SP.bhh[0] = (const float*)d_in[5];
  SP.bhh[1] = (const float*)d_in[9];
  SP.bhh[2] = (const float*)d_in[9] + G3;
  SP.bhh[3] = (const float*)d_in[13];
  SP.bhh[4] = (const float*)d_in[17];
  SP.bhh[5] = (const float*)d_in[17] + G3;

  for (int s = 0; s < NSTAGE; ++s) {
    k_stage<<<384, 256, 0, stream>>>(s, SP);
  }

  HeadParams HP;
  HP.Wmub = Wmub; HP.Wlvb = Wlvb; HP.hb0 = hb;
  HP.bmu = (const float*)d_in[19]; HP.blv = (const float*)d_in[21];
  HP.out = (float*)d_out;
  k_head<<<128, 256, 0, stream>>>(HP);
}